// Round 18
// baseline (125.671 us; speedup 1.0000x reference)
//
#include <hip/hip_runtime.h>
#include <hip/hip_bf16.h>

#define BATCH 16
#define D_OUT 1024
#define D_HID 512
#define D_FLT 13824
#define N0Q 9216
#define TW 14
#define TH 14
#define NXT 19
#define NYT 19
#define NB 2

typedef __attribute__((ext_vector_type(8))) short bf16x8;
typedef __attribute__((ext_vector_type(4))) float f32x4;

__device__ __forceinline__ float lrelu(float x) { return x >= 0.f ? x : 0.2f * x; }
__device__ __forceinline__ ushort f2bf(float x) {
  unsigned u = __float_as_uint(x);
  u += 0x7FFFu + ((u >> 16) & 1u);
  return (ushort)(u >> 16);
}
__device__ __forceinline__ float dot4(float4 a, float4 b) {
  return a.x * b.x + a.y * b.y + a.z * b.z + a.w * b.w;
}
__device__ __forceinline__ bf16x8 cvt8(const float* p) {
  float4 lo = *(const float4*)p;
  float4 hi = *(const float4*)(p + 4);
  bf16x8 r;
  r[0] = (short)f2bf(lo.x); r[1] = (short)f2bf(lo.y);
  r[2] = (short)f2bf(lo.z); r[3] = (short)f2bf(lo.w);
  r[4] = (short)f2bf(hi.x); r[5] = (short)f2bf(hi.y);
  r[6] = (short)f2bf(hi.z); r[7] = (short)f2bf(hi.w);
  return r;
}

// blocks [0,256): tex fp32 [32][256][256] -> bf16 pixel-major [256*256][32]
// blocks [256,768): fc1, 4 j per wave (z fragment register-resident, reused 4x)
__global__ void fc1_tex_kernel(const float* __restrict__ z, const float* __restrict__ W1,
                               const float* __restrict__ b1, float* __restrict__ h1,
                               const float* __restrict__ tex, ushort* __restrict__ texT) {
  int tid = threadIdx.x;
  if (blockIdx.x < 256) {
    int p = blockIdx.x * 256 + tid;
    unsigned pk[16];
    #pragma unroll
    for (int i = 0; i < 16; ++i) {
      ushort lo = f2bf(tex[(2 * i) * 65536 + p]);
      ushort hi = f2bf(tex[(2 * i + 1) * 65536 + p]);
      pk[i] = (unsigned)lo | ((unsigned)hi << 16);
    }
    uint4* dst = (uint4*)&texT[(size_t)p * 32];
    #pragma unroll
    for (int qq = 0; qq < 4; ++qq) {
      uint4 v; v.x = pk[qq * 4]; v.y = pk[qq * 4 + 1]; v.z = pk[qq * 4 + 2]; v.w = pk[qq * 4 + 3];
      dst[qq] = v;
    }
    return;
  }
  int w = tid >> 6, lane = tid & 63;
  int wid = (blockIdx.x - 256) * 4 + w;
  int b = wid >> 7, j0 = (wid & 127) * 4;
  const float4* zv = (const float4*)(z + b * D_OUT);
  float4 zr[4];
  #pragma unroll
  for (int i = 0; i < 4; ++i) zr[i] = zv[lane + i * 64];
  float s[4];
  #pragma unroll
  for (int jj = 0; jj < 4; ++jj) {
    const float4* wv = (const float4*)(W1 + (j0 + jj) * D_OUT);
    float t = 0.f;
    #pragma unroll
    for (int i = 0; i < 4; ++i) t += dot4(zr[i], wv[lane + i * 64]);
    s[jj] = t;
  }
  #pragma unroll
  for (int jj = 0; jj < 4; ++jj) {
    #pragma unroll
    for (int off = 32; off; off >>= 1) s[jj] += __shfl_xor(s[jj], off);
  }
  if (lane == 0) {
    #pragma unroll
    for (int jj = 0; jj < 4; ++jj)
      h1[b * D_HID + j0 + jj] = lrelu(s[jj] + b1[j0 + jj]);
  }
}

// fc2: 4 j per wave (512 blocks), h1 fragment register-resident.
__global__ void fc2_kernel(const float* __restrict__ in, const float* __restrict__ W,
                           const float* __restrict__ bias, float* __restrict__ out) {
  int tid = threadIdx.x;
  int w = tid >> 6, lane = tid & 63;
  int wid = blockIdx.x * 4 + w;
  int b = wid >> 7, j0 = (wid & 127) * 4;
  const float4* iv = (const float4*)(in + b * D_HID);
  float4 ir[2];
  #pragma unroll
  for (int i = 0; i < 2; ++i) ir[i] = iv[lane + i * 64];
  float s[4];
  #pragma unroll
  for (int jj = 0; jj < 4; ++jj) {
    const float4* wv = (const float4*)(W + (j0 + jj) * D_HID);
    float t = 0.f;
    #pragma unroll
    for (int i = 0; i < 2; ++i) t += dot4(ir[i], wv[lane + i * 64]);
    s[jj] = t;
  }
  #pragma unroll
  for (int jj = 0; jj < 4; ++jj) {
    #pragma unroll
    for (int off = 32; off; off >>= 1) s[jj] += __shfl_xor(s[jj], off);
  }
  if (lane == 0) {
    #pragma unroll
    for (int jj = 0; jj < 4; ++jj)
      out[b * D_HID + j0 + jj] = lrelu(s[jj] + bias[j0 + jj]);
  }
}

// fc3 as MFMA GEMM (proven R16: contiguous permuted store, W3 read once).
__global__ __launch_bounds__(256) void fc3_mfma(const float* __restrict__ h2,
                                                const float* __restrict__ W3,
                                                const float* __restrict__ b3,
                                                ushort* __restrict__ wbf) {
  const int tid = threadIdx.x;
  const int w = tid >> 6, lane = tid & 63;
  const int jn = lane & 15, q = lane >> 4;
  int t = blockIdx.x * 4 + w;
  int jbase, dstbase, ci0;
  if (t < 576) {
    int kp = t >> 6, rem = t & 63;
    int co = rem >> 1;
    ci0 = (rem & 1) * 16;
    jbase = co * 288 + kp;
    dstbase = kp * 1024 + co * 32 + ci0;
  } else {
    int t2 = t - 576;
    int kp = t2 >> 5, rem = t2 & 31;
    int co = rem >> 1;
    ci0 = (rem & 1) * 16;
    jbase = N0Q + co * 288 + kp;
    dstbase = N0Q + kp * 512 + co * 32 + ci0;
  }
  const float* wrow = W3 + (size_t)(jbase + (ci0 + jn) * 9) * D_HID;
  const float* hrow = h2 + jn * D_HID;
  f32x4 acc = {0.f, 0.f, 0.f, 0.f};
  #pragma unroll
  for (int ks = 0; ks < 16; ++ks) {
    int k0 = ks * 32 + q * 8;
    bf16x8 a = cvt8(wrow + k0);
    bf16x8 bv = cvt8(hrow + k0);
    acc = __builtin_amdgcn_mfma_f32_16x16x32_bf16(a, bv, acc, 0, 0, 0);
  }
  ushort4 o;
  o.x = f2bf(acc[0] + b3[jbase + (ci0 + q * 4 + 0) * 9]);
  o.y = f2bf(acc[1] + b3[jbase + (ci0 + q * 4 + 1) * 9]);
  o.z = f2bf(acc[2] + b3[jbase + (ci0 + q * 4 + 2) * 9]);
  o.w = f2bf(acc[3] + b3[jbase + (ci0 + q * 4 + 3) * 9]);
  *(ushort4*)&wbf[(size_t)jn * D_FLT + dstbase + q * 4] = o;
}

// Fused conv1+conv2, MFMA 16x16x32 bf16. Block = 14x14 tile x NB=2 batches.
// LDS 37.4 KB -> 4 blocks/CU (R14 geometry, proven 64us/33% occ).
// R18 change: conv1 uses 2-ROW windows (acc 2x2x4=16 regs) so the FULL
// 18-frag a0 (72 VGPR) loads ONCE per batch: peak ~115 regs fits the
// (256,4) 128 cap without spill; conv1 B-reads 36->24/batch, a0 global
// fetches halved vs the two-pass R14 scheme.
__global__ __launch_bounds__(256, 4) void conv_mfma(const ushort* __restrict__ texT,
                                                    const ushort* __restrict__ wbf,
                                                    float* __restrict__ out) {
  extern __shared__ ushort sm[];
  ushort* texs  = sm;            // 18 rows x 18 px x 32 ci = 10368 shorts
  ushort* inter = sm + 10368;    // 16 x 16 x 32 = 8192 + 128 pad
  const int tid = threadIdx.x;
  const int w = tid >> 6, lane = tid & 63;
  const int jn = lane & 15, q = lane >> 4;
  const int tx0 = blockIdx.x * TW, ty0 = blockIdx.y * TH;

  // tex tile (18x18 px) -> LDS (quad-swizzle j' = (j+(px>>1))&3), 0 outside
  for (int i = tid; i < 1296; i += 256) {
    int row = i / 72, c = i - row * 72;
    int px = c >> 2, j = c & 3;
    int gy = ty0 - 2 + row, gx = tx0 - 2 + px;
    int4 v; v.x = 0; v.y = 0; v.z = 0; v.w = 0;
    if (gy >= 0 && gy < 256 && gx >= 0 && gx < 256)
      v = ((const int4*)texT)[(gy * 256 + gx) * 4 + j];
    ((int4*)texs)[row * 72 + px * 4 + ((j + (px >> 1)) & 3)] = v;
  }
  __syncthreads();

  #pragma unroll 1
  for (int bb = 0; bb < NB; ++bb) {
    const int b = blockIdx.z * NB + bb;
    const ushort* wb = wbf + (size_t)b * D_FLT;

    // FULL conv1 A-frag set, once per batch (contiguous 1KB/wave, L2-hot)
    bf16x8 a0[9][2];
    #pragma unroll
    for (int kp = 0; kp < 9; ++kp)
      #pragma unroll
      for (int h = 0; h < 2; ++h)
        a0[kp][h] = *(const bf16x8*)&wb[(kp * 32 + h * 16 + jn) * 32 + q * 8];

    // protect inter while prev batch's conv2 still reads it
    if (bb) __syncthreads();

    // ---- conv1: 2-row windows; wave w does rows {4w,4w+1} then {4w+2,4w+3}.
    // Each iter: 4 tex rows read once (12 B-reads) feed 2 rows x 2 co-halves
    // (36 MFMAs). acc = 16 regs -> a0 stays resident.
    #pragma unroll
    for (int it = 0; it < 2; ++it) {
      const int r0 = 4 * w + 2 * it;
      f32x4 acc[2][2];
      #pragma unroll
      for (int i = 0; i < 2; ++i) {
        acc[i][0] = f32x4{0.f, 0.f, 0.f, 0.f};
        acc[i][1] = f32x4{0.f, 0.f, 0.f, 0.f};
      }
      #pragma unroll
      for (int kyp = 0; kyp < 4; ++kyp) {
        const ushort* trow = &texs[(r0 + kyp) * 576];
        bf16x8 Bf[3];
        #pragma unroll
        for (int kx = 0; kx < 3; ++kx) {
          int p = jn + kx;
          Bf[kx] = *(const bf16x8*)&trow[p * 32 + ((q + (p >> 1)) & 3) * 8];
        }
        #pragma unroll
        for (int i = 0; i < 2; ++i) {
          int ky = kyp - i;
          if (ky >= 0 && ky < 3) {
            #pragma unroll
            for (int kx = 0; kx < 3; ++kx) {
              acc[i][0] = __builtin_amdgcn_mfma_f32_16x16x32_bf16(a0[ky * 3 + kx][0], Bf[kx], acc[i][0], 0, 0, 0);
              acc[i][1] = __builtin_amdgcn_mfma_f32_16x16x32_bf16(a0[ky * 3 + kx][1], Bf[kx], acc[i][1], 0, 0, 0);
            }
          }
        }
      }
      // D: col=lane&15 (pixel), row=(lane>>4)*4+reg (co). Out-of-image inter
      // positions must be EXACT ZERO (reference conv2 zero-pads).
      #pragma unroll
      for (int i = 0; i < 2; ++i) {
        int r = r0 + i;
        int gy1 = ty0 - 1 + r, gx1 = tx0 - 1 + jn;
        bool inimg = (gy1 >= 0 && gy1 < 256 && gx1 >= 0 && gx1 < 256);
        ushort4 p0, p1;
        p0.x = f2bf(lrelu(acc[i][0][0])); p0.y = f2bf(lrelu(acc[i][0][1]));
        p0.z = f2bf(lrelu(acc[i][0][2])); p0.w = f2bf(lrelu(acc[i][0][3]));
        p1.x = f2bf(lrelu(acc[i][1][0])); p1.y = f2bf(lrelu(acc[i][1][1]));
        p1.z = f2bf(lrelu(acc[i][1][2])); p1.w = f2bf(lrelu(acc[i][1][3]));
        if (!inimg) {
          p0.x = p0.y = p0.z = p0.w = 0;
          p1.x = p1.y = p1.z = p1.w = 0;
        }
        int rec = r * 512 + jn * 32;
        int sub = (q & 1) * 4;
        *(ushort4*)&inter[rec + ((((q >> 1) + (jn >> 1)) & 3) * 8) + sub] = p0;
        *(ushort4*)&inter[rec + (((2 + (q >> 1) + (jn >> 1)) & 3) * 8) + sub] = p1;
      }
    }

    // conv2 A-frags loaded after conv1 (register-pressure phasing)
    __builtin_amdgcn_sched_barrier(0);
    bf16x8 a1[9];
    #pragma unroll
    for (int kp = 0; kp < 9; ++kp)
      a1[kp] = *(const bf16x8*)&wb[N0Q + (kp * 16 + jn) * 32 + q * 8];
    __syncthreads();

    // ---- conv2: wave owns output rows 4w..4w+3; inter window clamped to 15;
    // garbage store-masked. (R14 version, unchanged) ----
    {
      const int s2 = 4 * w;
      f32x4 c[4];
      #pragma unroll
      for (int i = 0; i < 4; ++i) c[i] = f32x4{0.f, 0.f, 0.f, 0.f};
      #pragma unroll
      for (int kyp = 0; kyp < 6; ++kyp) {
        int ir = s2 + kyp; if (ir > 15) ir = 15;
        const ushort* irow = &inter[ir * 512];
        bf16x8 Bf[3];
        #pragma unroll
        for (int kx = 0; kx < 3; ++kx) {
          int p = jn + kx;
          Bf[kx] = *(const bf16x8*)&irow[p * 32 + ((q + (p >> 1)) & 3) * 8];
        }
        #pragma unroll
        for (int i = 0; i < 4; ++i) {
          int ky = kyp - i;
          if (ky >= 0 && ky < 3) {
            #pragma unroll
            for (int kx = 0; kx < 3; ++kx)
              c[i] = __builtin_amdgcn_mfma_f32_16x16x32_bf16(a1[ky * 3 + kx], Bf[kx], c[i], 0, 0, 0);
          }
        }
      }
      int gx = tx0 + jn;
      if (jn < TW && gx < 256) {
        #pragma unroll
        for (int i = 0; i < 4; ++i) {
          int ro = s2 + i;
          int gy = ty0 + ro;
          if (ro < TH && gy < 256) {
            #pragma unroll
            for (int ci = 0; ci < 4; ++ci) {
              int co = q * 4 + ci;
              out[(((size_t)b * 16 + co) * 256 + gy) * 256 + gx] = c[i][ci];
            }
          }
        }
      }
    }
  }
}

extern "C" void kernel_launch(void* const* d_in, const int* in_sizes, int n_in,
                              void* d_out, int out_size, void* d_ws, size_t ws_size,
                              hipStream_t stream) {
  const float* z   = (const float*)d_in[0];
  const float* tex = (const float*)d_in[1];
  const float* W1  = (const float*)d_in[2];
  const float* b1  = (const float*)d_in[3];
  const float* W2  = (const float*)d_in[4];
  const float* b2  = (const float*)d_in[5];
  const float* W3  = (const float*)d_in[6];
  const float* b3  = (const float*)d_in[7];
  float* out = (float*)d_out;

  // ws layout (bytes): h1 [0,32768) | h2 [32768,65536) | wbf bf16 [65536,507904) | texT bf16 [507904,4702208)
  float*  h1   = (float*)d_ws;
  float*  h2   = (float*)((char*)d_ws + 32768);
  ushort* wbf  = (ushort*)((char*)d_ws + 65536);
  ushort* texT = (ushort*)((char*)d_ws + 507904);

  fc1_tex_kernel<<<768, 256, 0, stream>>>(z, W1, b1, h1, tex, texT);
  fc2_kernel<<<512, 256, 0, stream>>>(h1, W2, b2, h2);
  fc3_mfma<<<216, 256, 0, stream>>>(h2, W3, b3, wbf);

  dim3 grid(NXT, NYT, BATCH / NB);
  conv_mfma<<<grid, 256, (10368 + 8192 + 128) * sizeof(ushort), stream>>>(texT, wbf, out);
}

// Round 19
// 84.847 us; speedup vs baseline: 1.4812x; 1.4812x over previous
//
#include <hip/hip_runtime.h>
#include <hip/hip_bf16.h>

#define BATCH 16
#define D_OUT 1024
#define D_HID 512
#define D_FLT 13824
#define N0Q 9216
#define TW 14
#define TH 14
#define NXT 19
#define NYT 19
#define NB 2

typedef __attribute__((ext_vector_type(8))) short bf16x8;
typedef __attribute__((ext_vector_type(4))) float f32x4;

__device__ __forceinline__ float lrelu(float x) { return x >= 0.f ? x : 0.2f * x; }
__device__ __forceinline__ ushort f2bf(float x) {
  unsigned u = __float_as_uint(x);
  u += 0x7FFFu + ((u >> 16) & 1u);
  return (ushort)(u >> 16);
}
__device__ __forceinline__ float dot4(float4 a, float4 b) {
  return a.x * b.x + a.y * b.y + a.z * b.z + a.w * b.w;
}
__device__ __forceinline__ bf16x8 cvt8(const float* p) {
  float4 lo = *(const float4*)p;
  float4 hi = *(const float4*)(p + 4);
  bf16x8 r;
  r[0] = (short)f2bf(lo.x); r[1] = (short)f2bf(lo.y);
  r[2] = (short)f2bf(lo.z); r[3] = (short)f2bf(lo.w);
  r[4] = (short)f2bf(hi.x); r[5] = (short)f2bf(hi.y);
  r[6] = (short)f2bf(hi.z); r[7] = (short)f2bf(hi.w);
  return r;
}

// blocks [0,256): tex fp32 [32][256][256] -> bf16 pixel-major [256*256][32]
// blocks [256,768): fc1, 4 j per wave (z fragment register-resident, reused 4x)
__global__ void fc1_tex_kernel(const float* __restrict__ z, const float* __restrict__ W1,
                               const float* __restrict__ b1, float* __restrict__ h1,
                               const float* __restrict__ tex, ushort* __restrict__ texT) {
  int tid = threadIdx.x;
  if (blockIdx.x < 256) {
    int p = blockIdx.x * 256 + tid;
    unsigned pk[16];
    #pragma unroll
    for (int i = 0; i < 16; ++i) {
      ushort lo = f2bf(tex[(2 * i) * 65536 + p]);
      ushort hi = f2bf(tex[(2 * i + 1) * 65536 + p]);
      pk[i] = (unsigned)lo | ((unsigned)hi << 16);
    }
    uint4* dst = (uint4*)&texT[(size_t)p * 32];
    #pragma unroll
    for (int qq = 0; qq < 4; ++qq) {
      uint4 v; v.x = pk[qq * 4]; v.y = pk[qq * 4 + 1]; v.z = pk[qq * 4 + 2]; v.w = pk[qq * 4 + 3];
      dst[qq] = v;
    }
    return;
  }
  int w = tid >> 6, lane = tid & 63;
  int wid = (blockIdx.x - 256) * 4 + w;
  int b = wid >> 7, j0 = (wid & 127) * 4;
  const float4* zv = (const float4*)(z + b * D_OUT);
  float4 zr[4];
  #pragma unroll
  for (int i = 0; i < 4; ++i) zr[i] = zv[lane + i * 64];
  float s[4];
  #pragma unroll
  for (int jj = 0; jj < 4; ++jj) {
    const float4* wv = (const float4*)(W1 + (j0 + jj) * D_OUT);
    float t = 0.f;
    #pragma unroll
    for (int i = 0; i < 4; ++i) t += dot4(zr[i], wv[lane + i * 64]);
    s[jj] = t;
  }
  #pragma unroll
  for (int jj = 0; jj < 4; ++jj) {
    #pragma unroll
    for (int off = 32; off; off >>= 1) s[jj] += __shfl_xor(s[jj], off);
  }
  if (lane == 0) {
    #pragma unroll
    for (int jj = 0; jj < 4; ++jj)
      h1[b * D_HID + j0 + jj] = lrelu(s[jj] + b1[j0 + jj]);
  }
}

// fc2: 4 j per wave (512 blocks), h1 fragment register-resident.
__global__ void fc2_kernel(const float* __restrict__ in, const float* __restrict__ W,
                           const float* __restrict__ bias, float* __restrict__ out) {
  int tid = threadIdx.x;
  int w = tid >> 6, lane = tid & 63;
  int wid = blockIdx.x * 4 + w;
  int b = wid >> 7, j0 = (wid & 127) * 4;
  const float4* iv = (const float4*)(in + b * D_HID);
  float4 ir[2];
  #pragma unroll
  for (int i = 0; i < 2; ++i) ir[i] = iv[lane + i * 64];
  float s[4];
  #pragma unroll
  for (int jj = 0; jj < 4; ++jj) {
    const float4* wv = (const float4*)(W + (j0 + jj) * D_HID);
    float t = 0.f;
    #pragma unroll
    for (int i = 0; i < 2; ++i) t += dot4(ir[i], wv[lane + i * 64]);
    s[jj] = t;
  }
  #pragma unroll
  for (int jj = 0; jj < 4; ++jj) {
    #pragma unroll
    for (int off = 32; off; off >>= 1) s[jj] += __shfl_xor(s[jj], off);
  }
  if (lane == 0) {
    #pragma unroll
    for (int jj = 0; jj < 4; ++jj)
      out[b * D_HID + j0 + jj] = lrelu(s[jj] + bias[j0 + jj]);
  }
}

// fc3 as MFMA GEMM (proven R16: contiguous permuted store, W3 read once).
__global__ __launch_bounds__(256) void fc3_mfma(const float* __restrict__ h2,
                                                const float* __restrict__ W3,
                                                const float* __restrict__ b3,
                                                ushort* __restrict__ wbf) {
  const int tid = threadIdx.x;
  const int w = tid >> 6, lane = tid & 63;
  const int jn = lane & 15, q = lane >> 4;
  int t = blockIdx.x * 4 + w;
  int jbase, dstbase, ci0;
  if (t < 576) {
    int kp = t >> 6, rem = t & 63;
    int co = rem >> 1;
    ci0 = (rem & 1) * 16;
    jbase = co * 288 + kp;
    dstbase = kp * 1024 + co * 32 + ci0;
  } else {
    int t2 = t - 576;
    int kp = t2 >> 5, rem = t2 & 31;
    int co = rem >> 1;
    ci0 = (rem & 1) * 16;
    jbase = N0Q + co * 288 + kp;
    dstbase = N0Q + kp * 512 + co * 32 + ci0;
  }
  const float* wrow = W3 + (size_t)(jbase + (ci0 + jn) * 9) * D_HID;
  const float* hrow = h2 + jn * D_HID;
  f32x4 acc = {0.f, 0.f, 0.f, 0.f};
  #pragma unroll
  for (int ks = 0; ks < 16; ++ks) {
    int k0 = ks * 32 + q * 8;
    bf16x8 a = cvt8(wrow + k0);
    bf16x8 bv = cvt8(hrow + k0);
    acc = __builtin_amdgcn_mfma_f32_16x16x32_bf16(a, bv, acc, 0, 0, 0);
  }
  ushort4 o;
  o.x = f2bf(acc[0] + b3[jbase + (ci0 + q * 4 + 0) * 9]);
  o.y = f2bf(acc[1] + b3[jbase + (ci0 + q * 4 + 1) * 9]);
  o.z = f2bf(acc[2] + b3[jbase + (ci0 + q * 4 + 2) * 9]);
  o.w = f2bf(acc[3] + b3[jbase + (ci0 + q * 4 + 3) * 9]);
  *(ushort4*)&wbf[(size_t)jn * D_FLT + dstbase + q * 4] = o;
}

// Fused conv1+conv2, MFMA 16x16x32 bf16. Block = 14x14 tile x NB=2 batches.
// LDS 37.4 KB -> 4 blocks/CU; conv1 as TWO co-half passes (36-reg a0 each)
// so peak VGPR fits the (256,4) 128-reg cap without spill.
// PROVEN R14/R16 configuration: 64.3us, VGPR 64 (no scratch), Occ 33%.
// Rule from R5/R9/R18: 72-reg fragment arrays spill under cap 128 —
// only the 36-reg half-set survives. Do not re-widen.
__global__ __launch_bounds__(256, 4) void conv_mfma(const ushort* __restrict__ texT,
                                                    const ushort* __restrict__ wbf,
                                                    float* __restrict__ out) {
  extern __shared__ ushort sm[];
  ushort* texs  = sm;            // 18 rows x 18 px x 32 ci = 10368 shorts
  ushort* inter = sm + 10368;    // 16 x 16 x 32 = 8192 + 128 pad
  const int tid = threadIdx.x;
  const int w = tid >> 6, lane = tid & 63;
  const int jn = lane & 15, q = lane >> 4;
  const int tx0 = blockIdx.x * TW, ty0 = blockIdx.y * TH;

  // tex tile (18x18 px) -> LDS (quad-swizzle j' = (j+(px>>1))&3), 0 outside
  for (int i = tid; i < 1296; i += 256) {
    int row = i / 72, c = i - row * 72;
    int px = c >> 2, j = c & 3;
    int gy = ty0 - 2 + row, gx = tx0 - 2 + px;
    int4 v; v.x = 0; v.y = 0; v.z = 0; v.w = 0;
    if (gy >= 0 && gy < 256 && gx >= 0 && gx < 256)
      v = ((const int4*)texT)[(gy * 256 + gx) * 4 + j];
    ((int4*)texs)[row * 72 + px * 4 + ((j + (px >> 1)) & 3)] = v;
  }
  __syncthreads();

  const int s1 = 4 * w;   // conv1: wave owns inter rows 4w..4w+3 (16/4 even)

  #pragma unroll 1
  for (int bb = 0; bb < NB; ++bb) {
    const int b = blockIdx.z * NB + bb;
    const ushort* wb = wbf + (size_t)b * D_FLT;

    // protect inter while prev batch's conv2 still reads it
    if (bb) __syncthreads();

    // ---- conv1: two co-half passes (h=0: co 0..15, h=1: co 16..31) ----
    #pragma unroll 1
    for (int h = 0; h < 2; ++h) {
      bf16x8 a0[9];
      #pragma unroll
      for (int kp = 0; kp < 9; ++kp)
        a0[kp] = *(const bf16x8*)&wb[(kp * 32 + h * 16 + jn) * 32 + q * 8];

      f32x4 acc[4];
      #pragma unroll
      for (int i = 0; i < 4; ++i) acc[i] = f32x4{0.f, 0.f, 0.f, 0.f};
      #pragma unroll
      for (int kyp = 0; kyp < 6; ++kyp) {
        const ushort* trow = &texs[(s1 + kyp) * 576];
        bf16x8 Bf[3];
        #pragma unroll
        for (int kx = 0; kx < 3; ++kx) {
          int p = jn + kx;
          Bf[kx] = *(const bf16x8*)&trow[p * 32 + ((q + (p >> 1)) & 3) * 8];
        }
        #pragma unroll
        for (int i = 0; i < 4; ++i) {
          int ky = kyp - i;
          if (ky >= 0 && ky < 3) {
            #pragma unroll
            for (int kx = 0; kx < 3; ++kx)
              acc[i] = __builtin_amdgcn_mfma_f32_16x16x32_bf16(a0[ky * 3 + kx], Bf[kx], acc[i], 0, 0, 0);
          }
        }
      }
      // D: col=lane&15 (pixel), row=(lane>>4)*4+reg (co). Out-of-image inter
      // positions must be EXACT ZERO (reference conv2 zero-pads).
      #pragma unroll
      for (int i = 0; i < 4; ++i) {
        int r = s1 + i;
        int gy1 = ty0 - 1 + r, gx1 = tx0 - 1 + jn;
        bool inimg = (gy1 >= 0 && gy1 < 256 && gx1 >= 0 && gx1 < 256);
        ushort4 p0;
        p0.x = f2bf(lrelu(acc[i][0])); p0.y = f2bf(lrelu(acc[i][1]));
        p0.z = f2bf(lrelu(acc[i][2])); p0.w = f2bf(lrelu(acc[i][3]));
        if (!inimg) { p0.x = p0.y = p0.z = p0.w = 0; }
        *(ushort4*)&inter[r * 512 + jn * 32 +
                          (((2 * h + (q >> 1) + (jn >> 1)) & 3) * 8) + (q & 1) * 4] = p0;
      }
      __builtin_amdgcn_sched_barrier(0);   // keep pass-h+1 a0 out of pass-h liveness
    }

    // conv2 A-frags loaded after conv1 (register-pressure phasing)
    bf16x8 a1[9];
    #pragma unroll
    for (int kp = 0; kp < 9; ++kp)
      a1[kp] = *(const bf16x8*)&wb[N0Q + (kp * 16 + jn) * 32 + q * 8];
    __syncthreads();

    // ---- conv2: wave owns output rows 4w..4w+3; inter window clamped to 15;
    // garbage store-masked. ----
    {
      const int s2 = 4 * w;
      f32x4 c[4];
      #pragma unroll
      for (int i = 0; i < 4; ++i) c[i] = f32x4{0.f, 0.f, 0.f, 0.f};
      #pragma unroll
      for (int kyp = 0; kyp < 6; ++kyp) {
        int ir = s2 + kyp; if (ir > 15) ir = 15;
        const ushort* irow = &inter[ir * 512];
        bf16x8 Bf[3];
        #pragma unroll
        for (int kx = 0; kx < 3; ++kx) {
          int p = jn + kx;
          Bf[kx] = *(const bf16x8*)&irow[p * 32 + ((q + (p >> 1)) & 3) * 8];
        }
        #pragma unroll
        for (int i = 0; i < 4; ++i) {
          int ky = kyp - i;
          if (ky >= 0 && ky < 3) {
            #pragma unroll
            for (int kx = 0; kx < 3; ++kx)
              c[i] = __builtin_amdgcn_mfma_f32_16x16x32_bf16(a1[ky * 3 + kx], Bf[kx], c[i], 0, 0, 0);
          }
        }
      }
      int gx = tx0 + jn;
      if (jn < TW && gx < 256) {
        #pragma unroll
        for (int i = 0; i < 4; ++i) {
          int ro = s2 + i;
          int gy = ty0 + ro;
          if (ro < TH && gy < 256) {
            #pragma unroll
            for (int ci = 0; ci < 4; ++ci) {
              int co = q * 4 + ci;
              out[(((size_t)b * 16 + co) * 256 + gy) * 256 + gx] = c[i][ci];
            }
          }
        }
      }
    }
  }
}

extern "C" void kernel_launch(void* const* d_in, const int* in_sizes, int n_in,
                              void* d_out, int out_size, void* d_ws, size_t ws_size,
                              hipStream_t stream) {
  const float* z   = (const float*)d_in[0];
  const float* tex = (const float*)d_in[1];
  const float* W1  = (const float*)d_in[2];
  const float* b1  = (const float*)d_in[3];
  const float* W2  = (const float*)d_in[4];
  const float* b2  = (const float*)d_in[5];
  const float* W3  = (const float*)d_in[6];
  const float* b3  = (const float*)d_in[7];
  float* out = (float*)d_out;

  // ws layout (bytes): h1 [0,32768) | h2 [32768,65536) | wbf bf16 [65536,507904) | texT bf16 [507904,4702208)
  float*  h1   = (float*)d_ws;
  float*  h2   = (float*)((char*)d_ws + 32768);
  ushort* wbf  = (ushort*)((char*)d_ws + 65536);
  ushort* texT = (ushort*)((char*)d_ws + 507904);

  fc1_tex_kernel<<<768, 256, 0, stream>>>(z, W1, b1, h1, tex, texT);
  fc2_kernel<<<512, 256, 0, stream>>>(h1, W2, b2, h2);
  fc3_mfma<<<216, 256, 0, stream>>>(h2, W3, b3, wbf);

  dim3 grid(NXT, NYT, BATCH / NB);
  conv_mfma<<<grid, 256, (10368 + 8192 + 128) * sizeof(ushort), stream>>>(texT, wbf, out);
}